// Round 1
// baseline (1078.680 us; speedup 1.0000x reference)
//
#include <hip/hip_runtime.h>
#include <hip/hip_bf16.h>

// Problem constants (B=2, T=S=2048, EMBED=1024, H=16, D=64, top-k=204)
#define TT 2048
#define KTOP 204

typedef float f32x4 __attribute__((ext_vector_type(4)));
typedef short short8 __attribute__((ext_vector_type(8)));
typedef unsigned short u16;

#define NEG_INF (-__builtin_inff())

static __device__ __forceinline__ f32x4 mfma16(short8 a, short8 b, f32x4 c) {
  return __builtin_amdgcn_mfma_f32_16x16x32_bf16(a, b, c, 0, 0, 0);
}

static __device__ __forceinline__ u16 f2b(float f) {
  __hip_bfloat16 h = __float2bfloat16(f);
  return *reinterpret_cast<u16*>(&h);
}

static __device__ __forceinline__ unsigned fkey(float f) {
  unsigned u = __float_as_uint(f);
  return (u & 0x80000000u) ? ~u : (u | 0x80000000u);
}

#define GLOAD16(gp, lp) __builtin_amdgcn_global_load_lds( \
    (const __attribute__((address_space(1))) void*)(gp),  \
    (__attribute__((address_space(3))) void*)(lp), 16, 0, 0)

// wave-local LDS ordering fence (waves never cross-talk in the topk phase)
#define WSYNC() do { __builtin_amdgcn_wave_barrier(); \
    asm volatile("s_waitcnt lgkmcnt(0)" ::: "memory"); \
    __builtin_amdgcn_wave_barrier(); } while (0)

// ---------------- cast / transpose-cast kernels ----------------

__global__ __launch_bounds__(256) void k_cast(const float* __restrict__ in,
                                              u16* __restrict__ out, int n) {
  int i = (blockIdx.x * 256 + threadIdx.x) * 4;
  if (i < n) {
    f32x4 v = *(const f32x4*)(in + i);
    u16 r0 = f2b(v[0]), r1 = f2b(v[1]), r2 = f2b(v[2]), r3 = f2b(v[3]);
    out[i] = r0; out[i+1] = r1; out[i+2] = r2; out[i+3] = r3;
  }
}

// Wq[h][e][d] (f32) -> out[(h*64+d)*1024 + e] (bf16)  [Bt layout: row=n, col=k]
__global__ __launch_bounds__(256) void k_tw(const float* __restrict__ W,
                                            u16* __restrict__ out) {
  int i = blockIdx.x * 256 + threadIdx.x;
  if (i < 16 * 1024 * 64) {
    int d = i & 63, e = (i >> 6) & 1023, h = i >> 16;
    out[(h * 64 + d) * 1024 + e] = f2b(W[i]);
  }
}

// W_proj[k][n] (f32) -> out[n*1024 + k] (bf16)
__global__ __launch_bounds__(256) void k_tsq(const float* __restrict__ W,
                                             u16* __restrict__ out) {
  int i = blockIdx.x * 256 + threadIdx.x;
  if (i < 1024 * 1024) {
    int n = i & 1023, kk = i >> 10;
    out[n * 1024 + kk] = f2b(W[i]);
  }
}

// ---------------- bf16 MFMA GEMM: C[M=4096][N=1024] = A[M][K=1024] @ Bt[N][K]^T
// MODE 0: out bf16 at q/k layout [B][H][T][D]
// MODE 1: out bf16 at transposed v layout [B][H][D][T]
// MODE 2: out f32 [M][N] + bias[n]  (final projection)
template <int MODE>
__global__ __launch_bounds__(256) void gemm_bf16(
    const u16* __restrict__ A, const u16* __restrict__ Bt,
    void* __restrict__ outp, const float* __restrict__ bias) {
  __shared__ u16 lA[64 * 32];  // [m][k] 4KB
  __shared__ u16 lB[64 * 32];  // [n][k] 4KB
  const int K = 1024;
  int tid = threadIdx.x, w = tid >> 6, lane = tid & 63;
  int lr = lane & 15, lg = lane >> 4;
  int m0 = blockIdx.y * 64, n0 = blockIdx.x * 64;
  f32x4 acc[4] = {};

  const u16* ga = A + (size_t)(m0 + (tid >> 2)) * K + (tid & 3) * 8;
  const u16* gb = Bt + (size_t)(n0 + (tid >> 2)) * K + (tid & 3) * 8;
  char* lA_base = (char*)lA + w * 1024;  // wave-uniform; HW adds lane*16
  char* lB_base = (char*)lB + w * 1024;

  for (int kt = 0; kt < K; kt += 32) {
    __syncthreads();               // previous tile's reads done
    GLOAD16(ga + kt, lA_base);
    GLOAD16(gb + kt, lB_base);
    __syncthreads();               // compiler drains vmcnt before s_barrier
    short8 a = *(const short8*)&lA[(w * 16 + lr) * 32 + lg * 8];
#pragma unroll
    for (int j = 0; j < 4; ++j) {
      short8 b = *(const short8*)&lB[(j * 16 + lr) * 32 + lg * 8];
      acc[j] = mfma16(a, b, acc[j]);
    }
  }

  int mbase = m0 + w * 16 + lg * 4;
#pragma unroll
  for (int j = 0; j < 4; ++j) {
    int n = n0 + j * 16 + lr;
#pragma unroll
    for (int jj = 0; jj < 4; ++jj) {
      int m = mbase + jj;
      float v = acc[j][jj];
      if (MODE == 0) {
        int b = m >> 11, t = m & 2047, h = n >> 6, d = n & 63;
        ((u16*)outp)[(((size_t)(b * 16 + h)) * TT + t) * 64 + d] = f2b(v);
      } else if (MODE == 1) {
        int b = m >> 11, t = m & 2047, h = n >> 6, d = n & 63;
        ((u16*)outp)[(((size_t)(b * 16 + h)) * 64 + d) * TT + t] = f2b(v);
      } else {
        ((float*)outp)[(size_t)m * 1024 + n] = v + bias[n];
      }
    }
  }
}

// ---------------- fused scores + exact top-k + softmax + PV ----------------
// grid: (T/16, B*H).  One 16-q-row tile per block, 4 waves.
__global__ __launch_bounds__(256) void k_attn(
    const u16* __restrict__ qb, const u16* __restrict__ kb,
    const u16* __restrict__ vtb, u16* __restrict__ aob) {
  __shared__ float sc[16][2052];   // padded stride: banks spread, 16B aligned
  __shared__ int hist[4][256];
  __shared__ float rs[16];

  int tid = threadIdx.x, w = tid >> 6, lane = tid & 63;
  int lr = lane & 15, lg = lane >> 4;
  int t0 = blockIdx.x * 16;
  int bh = blockIdx.y;  // b*16 + h
  const u16* qh = qb + (size_t)bh * TT * 64;
  const u16* kh = kb + (size_t)bh * TT * 64;
  const u16* vh = vtb + (size_t)bh * 64 * TT;
  int SC = ((t0 + 16 + 31) >> 5) << 5;  // score cols rounded to PV k-step

  // Q fragments for this tile (A operand: row=lr, k-group=lg)
  short8 a0 = *(const short8*)&qh[(t0 + lr) * 64 + lg * 8];
  short8 a1 = *(const short8*)&qh[(t0 + lr) * 64 + 32 + lg * 8];

  // ---- scores: S[t][s] = (q.k) * 0.125, causal-masked, into LDS ----
  for (int s0 = w * 16; s0 < SC; s0 += 64) {
    short8 b0 = *(const short8*)&kh[(s0 + lr) * 64 + lg * 8];
    short8 b1 = *(const short8*)&kh[(s0 + lr) * 64 + 32 + lg * 8];
    f32x4 acc = {0.f, 0.f, 0.f, 0.f};
    acc = mfma16(a0, b0, acc);
    acc = mfma16(a1, b1, acc);
    int s = s0 + lr;
#pragma unroll
    for (int j = 0; j < 4; ++j) {
      int row = lg * 4 + j;
      float v = acc[j] * 0.125f;
      if (s > t0 + row) v = NEG_INF;
      sc[row][s] = v;
    }
  }
  __syncthreads();

  // ---- per-row exact top-204 threshold + softmax (wave w owns rows rr*4+w) --
  for (int rr = 0; rr < 4; ++rr) {
    int row = rr * 4 + w;
    int t = t0 + row, n = t + 1;
    float th = NEG_INF;
    if (n > KTOP) {  // wave-uniform branch
      unsigned prefix = 0;
      int k = KTOP;
#pragma unroll
      for (int pass = 0; pass < 4; ++pass) {
        int shift = 24 - pass * 8;
        int idx = lane * 4;
        hist[w][idx] = 0; hist[w][idx + 1] = 0;
        hist[w][idx + 2] = 0; hist[w][idx + 3] = 0;
        WSYNC();
        int sh2 = (pass == 0) ? 0 : (shift + 8);  // avoid shift-by-32 UB
        for (int s = lane; s < n; s += 64) {
          unsigned u = fkey(sc[row][s]);
          bool ok = (pass == 0) || ((u >> sh2) == prefix);
          if (ok) atomicAdd(&hist[w][(u >> shift) & 255], 1);
        }
        WSYNC();
        int h0 = hist[w][idx], h1 = hist[w][idx + 1];
        int h2 = hist[w][idx + 2], h3 = hist[w][idx + 3];
        int lsum = h0 + h1 + h2 + h3;
        int ssum = lsum;  // inclusive suffix sum across lanes
#pragma unroll
        for (int off = 1; off < 64; off <<= 1) {
          int o = __shfl_down(ssum, off);
          ssum += (lane + off < 64) ? o : 0;
        }
        int above = ssum - lsum;          // count in lanes > this one
        int cg3 = above;
        int cg2 = cg3 + h3;
        int cg1 = cg2 + h2;
        int cg0 = cg1 + h1;
        int dig = -1, nk = 0;
        if (cg0 < k && cg0 + h0 >= k) { dig = idx;     nk = k - cg0; }
        if (cg1 < k && cg1 + h1 >= k) { dig = idx + 1; nk = k - cg1; }
        if (cg2 < k && cg2 + h2 >= k) { dig = idx + 2; nk = k - cg2; }
        if (cg3 < k && cg3 + h3 >= k) { dig = idx + 3; nk = k - cg3; }
        unsigned long long ball = __ballot(dig >= 0);
        int src = __ffsll(ball) - 1;
        dig = __shfl(dig, src);
        nk = __shfl(nk, src);
        prefix = (prefix << 8) | (unsigned)dig;
        k = nk;
      }
      unsigned ubits = (prefix & 0x80000000u) ? (prefix ^ 0x80000000u) : ~prefix;
      th = __uint_as_float(ubits);  // exact kth-largest score value
    }
    // online softmax over kept entries; store p=exp(v-max) back, rs=1/sum
    float mx = NEG_INF;
    for (int s = lane; s < SC; s += 64) {
      float v = sc[row][s];
      mx = fmaxf(mx, v >= th ? v : NEG_INF);
    }
#pragma unroll
    for (int off = 32; off; off >>= 1) mx = fmaxf(mx, __shfl_xor(mx, off));
    float sum = 0.f;
    for (int s = lane; s < SC; s += 64) {
      float v = sc[row][s];
      float p = (v >= th) ? __expf(v - mx) : 0.f;
      sc[row][s] = p;
      sum += p;
    }
#pragma unroll
    for (int off = 32; off; off >>= 1) sum += __shfl_xor(sum, off);
    if (lane == 0) rs[row] = 1.f / sum;
  }
  __syncthreads();

  // ---- PV: O[t][d] = sum_s P[t][s] * V[s][d]; wave w owns d-cols w*16.. ----
  f32x4 o = {0.f, 0.f, 0.f, 0.f};
  int d0 = w * 16;
  for (int kk = 0; kk < SC; kk += 32) {
    f32x4 p0 = *(const f32x4*)&sc[lr][kk + lg * 8];
    f32x4 p1 = *(const f32x4*)&sc[lr][kk + lg * 8 + 4];
    short8 a;
    a[0] = (short)f2b(p0[0]); a[1] = (short)f2b(p0[1]);
    a[2] = (short)f2b(p0[2]); a[3] = (short)f2b(p0[3]);
    a[4] = (short)f2b(p1[0]); a[5] = (short)f2b(p1[1]);
    a[6] = (short)f2b(p1[2]); a[7] = (short)f2b(p1[3]);
    short8 b = *(const short8*)&vh[(size_t)(d0 + lr) * TT + kk + lg * 8];
    o = mfma16(a, b, o);
  }
  int b_ = bh >> 4, h_ = bh & 15;
#pragma unroll
  for (int j = 0; j < 4; ++j) {
    int row = lg * 4 + j;
    int t = t0 + row;
    float val = o[j] * rs[row];
    aob[((size_t)(b_ * TT + t)) * 1024 + h_ * 64 + d0 + lr] = f2b(val);
  }
}

// ---------------- launch ----------------

extern "C" void kernel_launch(void* const* d_in, const int* in_sizes, int n_in,
                              void* d_out, int out_size, void* d_ws, size_t ws_size,
                              hipStream_t stream) {
  const float* index  = (const float*)d_in[0];
  const float* memory = (const float*)d_in[1];
  const float* Wq     = (const float*)d_in[2];
  const float* Wk     = (const float*)d_in[3];
  const float* Wv     = (const float*)d_in[4];
  const float* Wp     = (const float*)d_in[5];
  const float* bp     = (const float*)d_in[6];

  char* ws = (char*)d_ws;
  const size_t MB = 1024 * 1024;
  // workspace layout (needs 48 MB)
  u16* xbi = (u16*)(ws + 0);        // index bf16 [4096][1024]   8MB
  u16* xbm = (u16*)(ws + 8 * MB);   // memory bf16               8MB
  u16* wqt = (u16*)(ws + 16 * MB);  // Wq^T bf16 [1024][1024]    2MB
  u16* wkt = (u16*)(ws + 18 * MB);
  u16* wvt = (u16*)(ws + 20 * MB);
  u16* wpt = (u16*)(ws + 22 * MB);
  u16* qb  = (u16*)(ws + 24 * MB);  // q  [B][H][T][64]          8MB
  u16* kbf = (u16*)(ws + 32 * MB);  // k  [B][H][T][64]          8MB
  u16* vtb = (u16*)(ws + 40 * MB);  // vt [B][H][64][T]          8MB
  u16* aob = xbi;                   // attn out [B][T][1024]; xbi free by then

  k_cast<<<4096, 256, 0, stream>>>(index, xbi, 4096 * 1024);
  k_cast<<<4096, 256, 0, stream>>>(memory, xbm, 4096 * 1024);
  k_tw<<<4096, 256, 0, stream>>>(Wq, wqt);
  k_tw<<<4096, 256, 0, stream>>>(Wk, wkt);
  k_tw<<<4096, 256, 0, stream>>>(Wv, wvt);
  k_tsq<<<4096, 256, 0, stream>>>(Wp, wpt);

  dim3 g(16, 64);  // N/64, M/64
  gemm_bf16<0><<<g, 256, 0, stream>>>(xbi, wqt, (void*)qb, nullptr);
  gemm_bf16<0><<<g, 256, 0, stream>>>(xbm, wkt, (void*)kbf, nullptr);
  gemm_bf16<1><<<g, 256, 0, stream>>>(xbm, wvt, (void*)vtb, nullptr);

  k_attn<<<dim3(TT / 16, 32), 256, 0, stream>>>(qb, kbf, vtb, aob);

  gemm_bf16<2><<<g, 256, 0, stream>>>(aob, wpt, d_out, bp);
}

// Round 2
// 390.535 us; speedup vs baseline: 2.7621x; 2.7621x over previous
//
#include <hip/hip_runtime.h>
#include <hip/hip_bf16.h>

// Problem constants (B=2, T=S=2048, EMBED=1024, H=16, D=64, top-k=204)
#define TT 2048
#define KTOP 204
#define ROWS 16
#define SCS 2056  // score row stride in bf16 (4112 B: 16B-aligned, 1028 dw)

typedef float f32x4 __attribute__((ext_vector_type(4)));
typedef short short8 __attribute__((ext_vector_type(8)));
typedef unsigned short u16;
typedef unsigned int u32;

#define NEG_INF (-__builtin_inff())

static __device__ __forceinline__ f32x4 mfma16(short8 a, short8 b, f32x4 c) {
  return __builtin_amdgcn_mfma_f32_16x16x32_bf16(a, b, c, 0, 0, 0);
}

static __device__ __forceinline__ u16 f2b(float f) {
  __hip_bfloat16 h = __float2bfloat16(f);
  return *reinterpret_cast<u16*>(&h);
}

static __device__ __forceinline__ float b2f(u32 b) {
  u32 u = b << 16;
  return __uint_as_float(u);
}

static __device__ __forceinline__ u32 fkey32(float f) {
  u32 u = __float_as_uint(f);
  return (u & 0x80000000u) ? ~u : (u | 0x80000000u);
}
static __device__ __forceinline__ float fkey32inv(u32 k) {
  u32 u = (k & 0x80000000u) ? (k ^ 0x80000000u) : ~k;
  return __uint_as_float(u);
}
static __device__ __forceinline__ u32 fkey16(u32 u) {  // u: 16-bit bf16 bits
  return (u & 0x8000u) ? (u ^ 0xFFFFu) : (u | 0x8000u);
}

#define GLOAD16(gp, lp) __builtin_amdgcn_global_load_lds( \
    (const __attribute__((address_space(1))) void*)(gp),  \
    (__attribute__((address_space(3))) void*)(lp), 16, 0, 0)

// wave-local LDS ordering fence
#define WSYNC() do { __builtin_amdgcn_wave_barrier(); \
    asm volatile("s_waitcnt lgkmcnt(0)" ::: "memory"); \
    __builtin_amdgcn_wave_barrier(); } while (0)

// Given this lane's 4 bin counts (bins 4*lane .. 4*lane+3, ascending), find
// the bin containing the k-th largest and the residual rank within it.
static __device__ __forceinline__ void radix_rank(int h0, int h1c, int h2c,
                                                  int h3c, int lane, int& k,
                                                  u32& digOut) {
  int lsum = h0 + h1c + h2c + h3c;
  int ssum = lsum;  // inclusive suffix sum across lanes
#pragma unroll
  for (int off = 1; off < 64; off <<= 1) {
    int o = __shfl_down(ssum, off);
    ssum += (lane + off < 64) ? o : 0;
  }
  int above = ssum - lsum;  // count in lanes above (higher bins)
  int cg3 = above;
  int cg2 = cg3 + h3c;
  int cg1 = cg2 + h2c;
  int cg0 = cg1 + h1c;
  int idx = lane * 4;
  int dig = -1, nk = 0;
  if (cg0 < k && cg0 + h0 >= k) { dig = idx;     nk = k - cg0; }
  if (cg1 < k && cg1 + h1c >= k) { dig = idx + 1; nk = k - cg1; }
  if (cg2 < k && cg2 + h2c >= k) { dig = idx + 2; nk = k - cg2; }
  if (cg3 < k && cg3 + h3c >= k) { dig = idx + 3; nk = k - cg3; }
  unsigned long long ball = __ballot(dig >= 0);
  int src = __ffsll(ball) - 1;
  dig = __shfl(dig, src);
  nk = __shfl(nk, src);
  digOut = (u32)dig;
  k = nk;
}

// ---------------- cast / transpose-cast kernels ----------------

__global__ __launch_bounds__(256) void k_cast(const float* __restrict__ in,
                                              u16* __restrict__ out, int n) {
  int i = (blockIdx.x * 256 + threadIdx.x) * 4;
  if (i < n) {
    f32x4 v = *(const f32x4*)(in + i);
    u16 r0 = f2b(v[0]), r1 = f2b(v[1]), r2 = f2b(v[2]), r3 = f2b(v[3]);
    out[i] = r0; out[i+1] = r1; out[i+2] = r2; out[i+3] = r3;
  }
}

__global__ __launch_bounds__(256) void k_tw(const float* __restrict__ W,
                                            u16* __restrict__ out) {
  int i = blockIdx.x * 256 + threadIdx.x;
  if (i < 16 * 1024 * 64) {
    int d = i & 63, e = (i >> 6) & 1023, h = i >> 16;
    out[(h * 64 + d) * 1024 + e] = f2b(W[i]);
  }
}

__global__ __launch_bounds__(256) void k_tsq(const float* __restrict__ W,
                                             u16* __restrict__ out) {
  int i = blockIdx.x * 256 + threadIdx.x;
  if (i < 1024 * 1024) {
    int n = i & 1023, kk = i >> 10;
    out[n * 1024 + kk] = f2b(W[i]);
  }
}

// ---------------- bf16 MFMA GEMM (unchanged from round 1) ----------------
template <int MODE>
__global__ __launch_bounds__(256) void gemm_bf16(
    const u16* __restrict__ A, const u16* __restrict__ Bt,
    void* __restrict__ outp, const float* __restrict__ bias) {
  __shared__ u16 lA[64 * 32];
  __shared__ u16 lB[64 * 32];
  const int K = 1024;
  int tid = threadIdx.x, w = tid >> 6, lane = tid & 63;
  int lr = lane & 15, lg = lane >> 4;
  int m0 = blockIdx.y * 64, n0 = blockIdx.x * 64;
  f32x4 acc[4] = {};

  const u16* ga = A + (size_t)(m0 + (tid >> 2)) * K + (tid & 3) * 8;
  const u16* gb = Bt + (size_t)(n0 + (tid >> 2)) * K + (tid & 3) * 8;
  char* lA_base = (char*)lA + w * 1024;
  char* lB_base = (char*)lB + w * 1024;

  for (int kt = 0; kt < K; kt += 32) {
    __syncthreads();
    GLOAD16(ga + kt, lA_base);
    GLOAD16(gb + kt, lB_base);
    __syncthreads();
    short8 a = *(const short8*)&lA[(w * 16 + lr) * 32 + lg * 8];
#pragma unroll
    for (int j = 0; j < 4; ++j) {
      short8 b = *(const short8*)&lB[(j * 16 + lr) * 32 + lg * 8];
      acc[j] = mfma16(a, b, acc[j]);
    }
  }

  int mbase = m0 + w * 16 + lg * 4;
#pragma unroll
  for (int j = 0; j < 4; ++j) {
    int n = n0 + j * 16 + lr;
#pragma unroll
    for (int jj = 0; jj < 4; ++jj) {
      int m = mbase + jj;
      float v = acc[j][jj];
      if (MODE == 0) {
        int b = m >> 11, t = m & 2047, h = n >> 6, d = n & 63;
        ((u16*)outp)[(((size_t)(b * 16 + h)) * TT + t) * 64 + d] = f2b(v);
      } else if (MODE == 1) {
        int b = m >> 11, t = m & 2047, h = n >> 6, d = n & 63;
        ((u16*)outp)[(((size_t)(b * 16 + h)) * 64 + d) * TT + t] = f2b(v);
      } else {
        ((float*)outp)[(size_t)m * 1024 + n] = v + bias[n];
      }
    }
  }
}

// ---------------- fused scores + exact top-k + softmax + PV ----------------
// 512 threads (8 waves), 16 q-rows per block, bf16 scores in LDS,
// 2-pass 8-bit radix select on the 16-bit bf16 sort key (pass 1 fused into QK).
__global__ __launch_bounds__(512, 4) void k_attn(
    const u16* __restrict__ qb, const u16* __restrict__ kb,
    const u16* __restrict__ vtb, u16* __restrict__ aob) {
  __shared__ u16 sc[ROWS * SCS];          // 65792 B, bf16 scores then p
  __shared__ u32 hbuf[ROWS * 128 + 8 * 128];  // 12288 B: h1[16][128] + h2[8][128]
                                              // (u16-packed counts); reused as
                                              // f32 po[2][16][68] for PV partials
  __shared__ u32 rowmaxk[ROWS];
  __shared__ float rs[ROWS];

  u32* h1 = hbuf;
  u32* h2 = hbuf + ROWS * 128;

  int tid = threadIdx.x, w = tid >> 6, lane = tid & 63;
  int lr = lane & 15, lg = lane >> 4;
  int t0 = blockIdx.x * ROWS;
  int bh = blockIdx.y;  // b*16 + h
  const u16* qh = qb + (size_t)bh * TT * 64;
  const u16* kh = kb + (size_t)bh * TT * 64;
  const u16* vh = vtb + (size_t)bh * 64 * TT;
  int SC = ((t0 + ROWS + 31) >> 5) << 5;  // cols rounded to PV k-step

  // zero pass-1 hists + row maxes
  for (int i = tid; i < ROWS * 128; i += 512) h1[i] = 0;
  if (tid < ROWS) rowmaxk[tid] = 0;

  // Q fragments (A operand: row=lr, k=lg*8..)
  short8 a0 = *(const short8*)&qh[(t0 + lr) * 64 + lg * 8];
  short8 a1 = *(const short8*)&qh[(t0 + lr) * 64 + 32 + lg * 8];
  __syncthreads();

  // ---- QK^T -> bf16 scores in LDS + fused pass-1 histogram + row max ----
  float m4[4] = {NEG_INF, NEG_INF, NEG_INF, NEG_INF};
  for (int s0 = w * 16; s0 < SC; s0 += 128) {
    short8 b0 = *(const short8*)&kh[(s0 + lr) * 64 + lg * 8];
    short8 b1 = *(const short8*)&kh[(s0 + lr) * 64 + 32 + lg * 8];
    f32x4 acc = {0.f, 0.f, 0.f, 0.f};
    acc = mfma16(a0, b0, acc);
    acc = mfma16(a1, b1, acc);
    int s = s0 + lr;
#pragma unroll
    for (int j = 0; j < 4; ++j) {
      int row = lg * 4 + j;
      float v = acc[j] * 0.125f;
      if (s > t0 + row) v = NEG_INF;
      u16 vb = f2b(v);
      sc[row * SCS + s] = vb;
      m4[j] = fmaxf(m4[j], v);
      u32 k16 = fkey16((u32)vb);
      u32 bin = k16 >> 8;
      atomicAdd(&h1[row * 128 + (bin >> 1)], 1u << ((bin & 1) << 4));
    }
  }
#pragma unroll
  for (int j = 0; j < 4; ++j) {
    float m = m4[j];
#pragma unroll
    for (int off = 1; off < 16; off <<= 1) m = fmaxf(m, __shfl_xor(m, off));
    if (lr == 0) atomicMax(&rowmaxk[lg * 4 + j], fkey32(m));
  }
  __syncthreads();

  // ---- per-row select (wave w owns rows w and w+8) + softmax p-scan ----
  for (int rr = 0; rr < 2; ++rr) {
    int row = w + rr * 8;
    int t = t0 + row, n = t + 1;
    u32 key_th = 0;  // keep-all when n <= KTOP
    if (n > KTOP) {  // wave-uniform
      // pass 1: consume fused histogram (bins 4*lane..4*lane+3)
      u32 w0 = h1[row * 128 + lane * 2];
      u32 w1 = h1[row * 128 + lane * 2 + 1];
      int k = KTOP;
      u32 d1;
      radix_rank((int)(w0 & 0xFFFF), (int)(w0 >> 16),
                 (int)(w1 & 0xFFFF), (int)(w1 >> 16), lane, k, d1);
      // pass 2: histogram low byte of entries whose high byte == d1
      h2[w * 128 + lane] = 0;
      h2[w * 128 + lane + 64] = 0;
      WSYNC();
      const u32* sp = (const u32*)&sc[row * SCS];
      int half = (n + 1) >> 1;
      for (int i = lane; i < half; i += 64) {
        u32 pr = sp[i];
        u32 k0 = fkey16(pr & 0xFFFFu);
        u32 k1 = fkey16(pr >> 16);
        if ((k0 >> 8) == d1)
          atomicAdd(&h2[w * 128 + ((k0 & 255u) >> 1)], 1u << ((k0 & 1u) << 4));
        if ((k1 >> 8) == d1)
          atomicAdd(&h2[w * 128 + ((k1 & 255u) >> 1)], 1u << ((k1 & 1u) << 4));
      }
      WSYNC();
      w0 = h2[w * 128 + lane * 2];
      w1 = h2[w * 128 + lane * 2 + 1];
      u32 d2;
      radix_rank((int)(w0 & 0xFFFF), (int)(w0 >> 16),
                 (int)(w1 & 0xFFFF), (int)(w1 >> 16), lane, k, d2);
      key_th = (d1 << 8) | d2;  // key of kth-largest bf16 score
    }
    // softmax: p = exp(v - mx) where key >= key_th, else 0; write p back
    float mx = fkey32inv(rowmaxk[row]);
    const u32* sp = (const u32*)&sc[row * SCS];
    u32* spw = (u32*)&sc[row * SCS];
    float sum = 0.f;
    for (int i = lane; i < (SC >> 1); i += 64) {
      u32 pr = sp[i];
      u32 e0 = pr & 0xFFFFu, e1 = pr >> 16;
      float p0 = 0.f, p1 = 0.f;
      if (fkey16(e0) >= key_th) p0 = __expf(b2f(e0) - mx);
      if (fkey16(e1) >= key_th) p1 = __expf(b2f(e1) - mx);
      sum += p0 + p1;
      spw[i] = (u32)f2b(p0) | ((u32)f2b(p1) << 16);
    }
#pragma unroll
    for (int off = 32; off; off >>= 1) sum += __shfl_xor(sum, off);
    if (lane == 0) rs[row] = 1.f / sum;
  }
  __syncthreads();

  // ---- PV: O[t][d] = sum_s P[t][s] * V^T[d][s]; 8 waves = 4 d-groups x 2 kk halves
  float* po = (float*)hbuf;  // [2][16][68] f32 partials (hists dead now)
  int d0 = (w & 3) * 16;
  int h = w >> 2;
  int tiles = SC >> 5;
  int mid = ((tiles + 1) >> 1) << 5;
  int kb0 = h ? mid : 0;
  int kb1 = h ? SC : mid;
  f32x4 o = {0.f, 0.f, 0.f, 0.f};
  for (int kk = kb0; kk < kb1; kk += 32) {
    short8 a = *(const short8*)&sc[lr * SCS + kk + lg * 8];
    short8 b = *(const short8*)&vh[(size_t)(d0 + lr) * TT + kk + lg * 8];
    o = mfma16(a, b, o);
  }
#pragma unroll
  for (int j = 0; j < 4; ++j)
    po[(h * ROWS + lg * 4 + j) * 68 + d0 + lr] = o[j];
  __syncthreads();

  if (w < 4) {
    int b_ = bh >> 4, h_ = bh & 15;
    int dd0 = w * 16;
#pragma unroll
    for (int j = 0; j < 4; ++j) {
      int row = lg * 4 + j;
      float val = (po[row * 68 + dd0 + lr] + po[(ROWS + row) * 68 + dd0 + lr]) *
                  rs[row];
      aob[((size_t)(b_ * TT + t0 + row)) * 1024 + h_ * 64 + dd0 + lr] = f2b(val);
    }
  }
}

// ---------------- launch ----------------

extern "C" void kernel_launch(void* const* d_in, const int* in_sizes, int n_in,
                              void* d_out, int out_size, void* d_ws, size_t ws_size,
                              hipStream_t stream) {
  const float* index  = (const float*)d_in[0];
  const float* memory = (const float*)d_in[1];
  const float* Wq     = (const float*)d_in[2];
  const float* Wk     = (const float*)d_in[3];
  const float* Wv     = (const float*)d_in[4];
  const float* Wp     = (const float*)d_in[5];
  const float* bp     = (const float*)d_in[6];

  char* ws = (char*)d_ws;
  const size_t MB = 1024 * 1024;
  u16* xbi = (u16*)(ws + 0);
  u16* xbm = (u16*)(ws + 8 * MB);
  u16* wqt = (u16*)(ws + 16 * MB);
  u16* wkt = (u16*)(ws + 18 * MB);
  u16* wvt = (u16*)(ws + 20 * MB);
  u16* wpt = (u16*)(ws + 22 * MB);
  u16* qb  = (u16*)(ws + 24 * MB);
  u16* kbf = (u16*)(ws + 32 * MB);
  u16* vtb = (u16*)(ws + 40 * MB);
  u16* aob = xbi;  // reuse

  k_cast<<<4096, 256, 0, stream>>>(index, xbi, 4096 * 1024);
  k_cast<<<4096, 256, 0, stream>>>(memory, xbm, 4096 * 1024);
  k_tw<<<4096, 256, 0, stream>>>(Wq, wqt);
  k_tw<<<4096, 256, 0, stream>>>(Wk, wkt);
  k_tw<<<4096, 256, 0, stream>>>(Wv, wvt);
  k_tsq<<<4096, 256, 0, stream>>>(Wp, wpt);

  dim3 g(16, 64);
  gemm_bf16<0><<<g, 256, 0, stream>>>(xbi, wqt, (void*)qb, nullptr);
  gemm_bf16<0><<<g, 256, 0, stream>>>(xbm, wkt, (void*)kbf, nullptr);
  gemm_bf16<1><<<g, 256, 0, stream>>>(xbm, wvt, (void*)vtb, nullptr);

  k_attn<<<dim3(TT / ROWS, 32), 512, 0, stream>>>(qb, kbf, vtb, aob);

  gemm_bf16<2><<<g, 256, 0, stream>>>(aob, wpt, d_out, bp);
}

// Round 3
// 375.777 us; speedup vs baseline: 2.8705x; 1.0393x over previous
//
#include <hip/hip_runtime.h>
#include <hip/hip_bf16.h>

// Problem constants (B=2, T=S=2048, EMBED=1024, H=16, D=64, top-k=204)
#define TT 2048
#define KTOP 204
#define ROWS 16
#define SCS 2056  // u16 stride per score row (4112 B, 16B-aligned)

typedef float f32x4 __attribute__((ext_vector_type(4)));
typedef short short8 __attribute__((ext_vector_type(8)));
typedef unsigned short u16;
typedef unsigned int u32;
typedef u32 u32x2 __attribute__((ext_vector_type(2)));
typedef u32 u32x4 __attribute__((ext_vector_type(4)));

#define NEG_INF (-__builtin_inff())

static __device__ __forceinline__ f32x4 mfma16(short8 a, short8 b, f32x4 c) {
  return __builtin_amdgcn_mfma_f32_16x16x32_bf16(a, b, c, 0, 0, 0);
}

static __device__ __forceinline__ u16 f2b(float f) {
  __hip_bfloat16 h = __float2bfloat16(f);
  return *reinterpret_cast<u16*>(&h);
}

#define GLOAD16(gp, lp) __builtin_amdgcn_global_load_lds( \
    (const __attribute__((address_space(1))) void*)(gp),  \
    (__attribute__((address_space(3))) void*)(lp), 16, 0, 0)

// wave-local LDS ordering fence (per-wave private buffers only)
#define WSYNC() do { __builtin_amdgcn_wave_barrier(); \
    asm volatile("s_waitcnt lgkmcnt(0)" ::: "memory"); \
    __builtin_amdgcn_wave_barrier(); } while (0)

// 16-bin rank: cnt valid on lanes 0..15 (0 elsewhere). Returns the bin
// holding the k-th largest (counting from bin 15 down) and residual rank.
static __device__ __forceinline__ void rank16(u32 cnt, int lane, int& k,
                                              u32& dig) {
  int suf = (int)cnt;  // inclusive suffix sum over bins lane..15
#pragma unroll
  for (int off = 1; off < 16; off <<= 1) {
    int o = __shfl_down(suf, off);
    suf += (lane + off < 64) ? o : 0;
  }
  int above = suf - (int)cnt;
  bool found = (lane < 16) && (above < k) && (above + (int)cnt >= k);
  unsigned long long ball = __ballot(found);
  int src = __ffsll((long long)ball) - 1;
  int nk = k - above;
  k = __shfl(nk, src);
  dig = (u32)src;
}

// ---------------- cast / transpose-cast kernels ----------------

__global__ __launch_bounds__(256) void k_cast(const float* __restrict__ in,
                                              u16* __restrict__ out, int n) {
  int i = (blockIdx.x * 256 + threadIdx.x) * 4;
  if (i < n) {
    f32x4 v = *(const f32x4*)(in + i);
    u16 r0 = f2b(v[0]), r1 = f2b(v[1]), r2 = f2b(v[2]), r3 = f2b(v[3]);
    out[i] = r0; out[i+1] = r1; out[i+2] = r2; out[i+3] = r3;
  }
}

__global__ __launch_bounds__(256) void k_tw(const float* __restrict__ W,
                                            u16* __restrict__ out) {
  int i = blockIdx.x * 256 + threadIdx.x;
  if (i < 16 * 1024 * 64) {
    int d = i & 63, e = (i >> 6) & 1023, h = i >> 16;
    out[(h * 64 + d) * 1024 + e] = f2b(W[i]);
  }
}

__global__ __launch_bounds__(256) void k_tsq(const float* __restrict__ W,
                                             u16* __restrict__ out) {
  int i = blockIdx.x * 256 + threadIdx.x;
  if (i < 1024 * 1024) {
    int n = i & 1023, kk = i >> 10;
    out[n * 1024 + kk] = f2b(W[i]);
  }
}

// ---------------- bf16 MFMA GEMM ----------------
// MODE 0: out bf16 [B][H][T][D], value scaled by ascale
// MODE 1: out bf16 transposed [B][H][D][T]
// MODE 2: out f32 [M][N] + bias[n]
template <int MODE>
__global__ __launch_bounds__(256) void gemm_bf16(
    const u16* __restrict__ A, const u16* __restrict__ Bt,
    void* __restrict__ outp, const float* __restrict__ bias, float ascale) {
  __shared__ u16 lA[64 * 32];
  __shared__ u16 lB[64 * 32];
  const int K = 1024;
  int tid = threadIdx.x, w = tid >> 6, lane = tid & 63;
  int lr = lane & 15, lg = lane >> 4;
  int m0 = blockIdx.y * 64, n0 = blockIdx.x * 64;
  f32x4 acc[4] = {};

  const u16* ga = A + (size_t)(m0 + (tid >> 2)) * K + (tid & 3) * 8;
  const u16* gb = Bt + (size_t)(n0 + (tid >> 2)) * K + (tid & 3) * 8;
  char* lA_base = (char*)lA + w * 1024;
  char* lB_base = (char*)lB + w * 1024;

  for (int kt = 0; kt < K; kt += 32) {
    __syncthreads();
    GLOAD16(ga + kt, lA_base);
    GLOAD16(gb + kt, lB_base);
    __syncthreads();
    short8 a = *(const short8*)&lA[(w * 16 + lr) * 32 + lg * 8];
#pragma unroll
    for (int j = 0; j < 4; ++j) {
      short8 b = *(const short8*)&lB[(j * 16 + lr) * 32 + lg * 8];
      acc[j] = mfma16(a, b, acc[j]);
    }
  }

  int mbase = m0 + w * 16 + lg * 4;
#pragma unroll
  for (int j = 0; j < 4; ++j) {
    int n = n0 + j * 16 + lr;
#pragma unroll
    for (int jj = 0; jj < 4; ++jj) {
      int m = mbase + jj;
      float v = acc[j][jj];
      if (MODE == 0) {
        int b = m >> 11, t = m & 2047, h = n >> 6, d = n & 63;
        ((u16*)outp)[(((size_t)(b * 16 + h)) * TT + t) * 64 + d] = f2b(v * ascale);
      } else if (MODE == 1) {
        int b = m >> 11, t = m & 2047, h = n >> 6, d = n & 63;
        ((u16*)outp)[(((size_t)(b * 16 + h)) * 64 + d) * TT + t] = f2b(v);
      } else {
        ((float*)outp)[(size_t)m * 1024 + n] = v + bias[n];
      }
    }
  }
}

// ---------------- fused scores + exact top-k + softmax + PV ----------------
// 512 threads (8 waves), 16 q-rows/block. Scores stored as linear u16 keys
// (key = clamp(score*4096+32768)); swapped-operand QK so each lane owns 4
// consecutive s of one q-row; 4x4-bit radix select (pass 1 fused into QK,
// passes 2-4 from a register-held row copy).
__global__ __launch_bounds__(512, 4) void k_attn(
    const u16* __restrict__ qb, const u16* __restrict__ kb,
    const u16* __restrict__ vtb, u16* __restrict__ aob) {
  __shared__ u16 sc[ROWS * SCS];    // 65792 B: keys, then p (bf16)
  __shared__ u32 hist1[ROWS * 16];  // 1024 B  (QK-fused 4-bit histogram)
  __shared__ u32 hist2[8 * 16];     // 512 B   (per-wave refine histogram)
  __shared__ u32 rowmaxk[ROWS];
  __shared__ float rs[ROWS];
  __shared__ float po[2 * ROWS * 68];  // 8704 B PV partials
  // total LDS = 76160 B -> 2 blocks/CU

  int tid = threadIdx.x, w = tid >> 6, lane = tid & 63;
  int lr = lane & 15, lg = lane >> 4;
  int t0 = blockIdx.x * ROWS;
  int bh = blockIdx.y;  // b*16 + h
  const u16* qh = qb + (size_t)bh * TT * 64;
  const u16* kh = kb + (size_t)bh * TT * 64;
  const u16* vh = vtb + (size_t)bh * 64 * TT;
  int SC = ((t0 + ROWS + 31) >> 5) << 5;  // cols rounded to PV k-step

  if (tid < ROWS * 16) hist1[tid] = 0;
  if (tid < ROWS) rowmaxk[tid] = 0;

  // Q fragments (B operand: col=q-row=lr, k=lg*8..). q is pre-scaled by 1/8.
  short8 qf0 = *(const short8*)&qh[(size_t)(t0 + lr) * 64 + lg * 8];
  short8 qf1 = *(const short8*)&qh[(size_t)(t0 + lr) * 64 + 32 + lg * 8];
  __syncthreads();

  // ---- QK^T (swapped: C[s][q]) -> u16 keys in LDS + 4-bit hist + row max --
  u32 kmax = 0;
  for (int s0 = w * 16; s0 < SC; s0 += 128) {
    int t = t0 + lr;       // this lane's q row
    int sbase = s0 + lg * 4;
    u32 lo, hi;
    if (s0 > t0 + 15) {    // tile entirely above diagonal: all masked
      lo = 0; hi = 0;
    } else {
      short8 kf0 = *(const short8*)&kh[(size_t)(s0 + lr) * 64 + lg * 8];
      short8 kf1 = *(const short8*)&kh[(size_t)(s0 + lr) * 64 + 32 + lg * 8];
      f32x4 acc = {0.f, 0.f, 0.f, 0.f};
      acc = mfma16(kf0, qf0, acc);  // A = K rows (s), B = Q rows (cols)
      acc = mfma16(kf1, qf1, acc);
      u32 key[4];
#pragma unroll
      for (int j = 0; j < 4; ++j) {
        float kf = fmaf(acc[j], 4096.f, 32768.f);
        kf = fminf(fmaxf(kf, 0.f), 65535.f);
        key[j] = (u32)kf;
        if (sbase + j > t) key[j] = 0;  // causal mask -> minimal key
      }
      kmax = max(kmax, max(max(key[0], key[1]), max(key[2], key[3])));
#pragma unroll
      for (int j = 0; j < 4; ++j)
        atomicAdd(&hist1[lr * 16 + (key[j] >> 12)], 1u);
      lo = key[0] | (key[1] << 16);
      hi = key[2] | (key[3] << 16);
    }
    *(u32x2*)&sc[lr * SCS + sbase] = (u32x2){lo, hi};
  }
  // zero-fill [SC, 2048) so register row-scans see key 0 there
  for (int r = 0; r < ROWS; ++r)
    for (int s = SC + tid * 8; s < 2048; s += 512 * 8)
      *(u32x4*)&sc[r * SCS + s] = (u32x4){0, 0, 0, 0};
  // per-row key max: lanes {lr, lr+16, lr+32, lr+48} share a row
  kmax = max(kmax, (u32)__shfl_xor((int)kmax, 16));
  kmax = max(kmax, (u32)__shfl_xor((int)kmax, 32));
  if (lane < 16) atomicMax(&rowmaxk[lane], kmax);
  __syncthreads();

  // ---- per-row select + softmax (wave w owns rows w and w+8) ----
  for (int rr = 0; rr < 2; ++rr) {
    int row = w + rr * 8;
    int t = t0 + row, n = t + 1;
    // load full row (2048 keys) into registers: lane covers s=[lane*32,+32)
    u32 rv[16];
    const u32x4* rp = (const u32x4*)&sc[row * SCS + lane * 32];
#pragma unroll
    for (int i = 0; i < 4; ++i) {
      u32x4 v = rp[i];
      rv[i * 4 + 0] = v[0]; rv[i * 4 + 1] = v[1];
      rv[i * 4 + 2] = v[2]; rv[i * 4 + 3] = v[3];
    }
    u32 keyth = 0;
    if (n > KTOP) {  // wave-uniform branch
      int k = KTOP;
      u32 dig;
      rank16((lane < 16) ? hist1[row * 16 + lane] : 0u, lane, k, dig);
      u32 pfx = dig;
      for (int sh = 8; sh >= 0; sh -= 4) {
        if (lane < 16) hist2[w * 16 + lane] = 0;
        WSYNC();
        u32 ps = (u32)(sh + 4);
#pragma unroll
        for (int i = 0; i < 16; ++i) {
          u32 pr = rv[i];
          u32 e0 = pr & 0xFFFFu, e1 = pr >> 16;
          if ((e0 >> ps) == pfx)
            atomicAdd(&hist2[w * 16 + ((e0 >> sh) & 15u)], 1u);
          if ((e1 >> ps) == pfx)
            atomicAdd(&hist2[w * 16 + ((e1 >> sh) & 15u)], 1u);
        }
        WSYNC();
        rank16((lane < 16) ? hist2[w * 16 + lane] : 0u, lane, k, dig);
        pfx = (pfx << 4) | dig;
      }
      keyth = pfx;  // key of kth-largest (quantized) score
    }
    u32 thr = keyth > 1u ? keyth : 1u;  // never keep masked (key 0) entries
    u32 kmx = rowmaxk[row];
    const float c2 = 1.44269504f / 4096.f;
    float sum = 0.f;
#pragma unroll
    for (int i = 0; i < 16; ++i) {
      u32 pr = rv[i];
      u32 e0 = pr & 0xFFFFu, e1 = pr >> 16;
      float p0 = (e0 >= thr) ? exp2f((float)(int)(e0 - kmx) * c2) : 0.f;
      float p1 = (e1 >= thr) ? exp2f((float)(int)(e1 - kmx) * c2) : 0.f;
      sum += p0 + p1;
      rv[i] = (u32)f2b(p0) | ((u32)f2b(p1) << 16);
    }
#pragma unroll
    for (int off = 32; off; off >>= 1) sum += __shfl_xor(sum, off);
    // write p (bf16) back over the row
    u32x4* wp = (u32x4*)&sc[row * SCS + lane * 32];
#pragma unroll
    for (int i = 0; i < 4; ++i)
      wp[i] = (u32x4){rv[i * 4 + 0], rv[i * 4 + 1],
                      rv[i * 4 + 2], rv[i * 4 + 3]};
    if (lane == 0) rs[row] = 1.f / sum;
  }
  __syncthreads();

  // ---- PV: O[t][d] = sum_s P[t][s] V[s][d]; 4 d-groups x 2 k-halves ----
  int d0 = (w & 3) * 16;
  int h = w >> 2;
  int tiles = SC >> 5;
  int mid = ((tiles + 1) >> 1) << 5;
  int kb0 = h ? mid : 0;
  int kb1 = h ? SC : mid;
  f32x4 o = {0.f, 0.f, 0.f, 0.f};
  for (int kk = kb0; kk < kb1; kk += 32) {
    short8 a = *(const short8*)&sc[lr * SCS + kk + lg * 8];
    short8 b = *(const short8*)&vh[(size_t)(d0 + lr) * TT + kk + lg * 8];
    o = mfma16(a, b, o);
  }
#pragma unroll
  for (int j = 0; j < 4; ++j)
    po[(h * ROWS + lg * 4 + j) * 68 + d0 + lr] = o[j];
  __syncthreads();

  if (w < 4) {
    int b_ = bh >> 4, h_ = bh & 15;
    int dd0 = w * 16;
#pragma unroll
    for (int j = 0; j < 4; ++j) {
      int row = lg * 4 + j;
      float val = (po[row * 68 + dd0 + lr] + po[(ROWS + row) * 68 + dd0 + lr]) *
                  rs[row];
      aob[((size_t)(b_ * TT + t0 + row)) * 1024 + h_ * 64 + dd0 + lr] = f2b(val);
    }
  }
}

// ---------------- launch ----------------

extern "C" void kernel_launch(void* const* d_in, const int* in_sizes, int n_in,
                              void* d_out, int out_size, void* d_ws, size_t ws_size,
                              hipStream_t stream) {
  const float* index  = (const float*)d_in[0];
  const float* memory = (const float*)d_in[1];
  const float* Wq     = (const float*)d_in[2];
  const float* Wk     = (const float*)d_in[3];
  const float* Wv     = (const float*)d_in[4];
  const float* Wp     = (const float*)d_in[5];
  const float* bp     = (const float*)d_in[6];

  char* ws = (char*)d_ws;
  const size_t MB = 1024 * 1024;
  u16* xbi = (u16*)(ws + 0);
  u16* xbm = (u16*)(ws + 8 * MB);
  u16* wqt = (u16*)(ws + 16 * MB);
  u16* wkt = (u16*)(ws + 18 * MB);
  u16* wvt = (u16*)(ws + 20 * MB);
  u16* wpt = (u16*)(ws + 22 * MB);
  u16* qb  = (u16*)(ws + 24 * MB);
  u16* kbf = (u16*)(ws + 32 * MB);
  u16* vtb = (u16*)(ws + 40 * MB);
  u16* aob = xbi;  // reuse

  k_cast<<<4096, 256, 0, stream>>>(index, xbi, 4096 * 1024);
  k_cast<<<4096, 256, 0, stream>>>(memory, xbm, 4096 * 1024);
  k_tw<<<4096, 256, 0, stream>>>(Wq, wqt);
  k_tw<<<4096, 256, 0, stream>>>(Wk, wkt);
  k_tw<<<4096, 256, 0, stream>>>(Wv, wvt);
  k_tsq<<<4096, 256, 0, stream>>>(Wp, wpt);

  dim3 g(16, 64);
  // q is pre-scaled by HEAD^-0.5 = 0.125 so QK^T yields final scores
  gemm_bf16<0><<<g, 256, 0, stream>>>(xbi, wqt, (void*)qb, nullptr, 0.125f);
  gemm_bf16<0><<<g, 256, 0, stream>>>(xbm, wkt, (void*)kbf, nullptr, 1.f);
  gemm_bf16<1><<<g, 256, 0, stream>>>(xbm, wvt, (void*)vtb, nullptr, 1.f);

  k_attn<<<dim3(TT / ROWS, 32), 512, 0, stream>>>(qb, kbf, vtb, aob);

  gemm_bf16<2><<<g, 256, 0, stream>>>(aob, wpt, d_out, bp, 1.f);
}

// Round 4
// 357.614 us; speedup vs baseline: 3.0163x; 1.0508x over previous
//
#include <hip/hip_runtime.h>
#include <hip/hip_bf16.h>

// Problem constants (B=2, T=S=2048, EMBED=1024, H=16, D=64, top-k=204)
#define TT 2048
#define KTOP 204
#define ROWS 16
#define SCS 2056  // u16 stride per score row (4112 B, 16B-aligned)

typedef float f32x4 __attribute__((ext_vector_type(4)));
typedef short short8 __attribute__((ext_vector_type(8)));
typedef unsigned short u16;
typedef unsigned int u32;
typedef u32 u32x2 __attribute__((ext_vector_type(2)));
typedef u32 u32x4 __attribute__((ext_vector_type(4)));

#define NEG_INF (-__builtin_inff())

static __device__ __forceinline__ f32x4 mfma16(short8 a, short8 b, f32x4 c) {
  return __builtin_amdgcn_mfma_f32_16x16x32_bf16(a, b, c, 0, 0, 0);
}

static __device__ __forceinline__ u16 f2b(float f) {
  __hip_bfloat16 h = __float2bfloat16(f);
  return *reinterpret_cast<u16*>(&h);
}

#define GLOAD16(gp, lp) __builtin_amdgcn_global_load_lds( \
    (const __attribute__((address_space(1))) void*)(gp),  \
    (__attribute__((address_space(3))) void*)(lp), 16, 0, 0)

// wave-local LDS ordering fence (per-wave private buffers only)
#define WSYNC() do { __builtin_amdgcn_wave_barrier(); \
    asm volatile("s_waitcnt lgkmcnt(0)" ::: "memory"); \
    __builtin_amdgcn_wave_barrier(); } while (0)

// 64-bin rank: cnt per lane (bin = lane). Finds the bin holding the k-th
// largest (counting from bin 63 down); k becomes the residual rank in-bin.
static __device__ __forceinline__ void rank64(u32 cnt, int lane, int& k,
                                              u32& dig) {
  int suf = (int)cnt;  // inclusive suffix sum over bins lane..63
#pragma unroll
  for (int off = 1; off < 64; off <<= 1) {
    int o = __shfl_down(suf, off);
    suf += (lane + off < 64) ? o : 0;
  }
  int above = suf - (int)cnt;  // count in bins above this lane's
  bool found = (above < k) && (above + (int)cnt >= k);  // unique lane
  unsigned long long ball = __ballot(found);
  int src = __ffsll((long long)ball) - 1;
  int nk = k - above;
  k = __shfl(nk, src);
  dig = (u32)src;
}

// ---------------- cast / transpose-cast kernels ----------------

__global__ __launch_bounds__(256) void k_cast(const float* __restrict__ in,
                                              u16* __restrict__ out, int n) {
  int i = (blockIdx.x * 256 + threadIdx.x) * 4;
  if (i < n) {
    f32x4 v = *(const f32x4*)(in + i);
    u16 r0 = f2b(v[0]), r1 = f2b(v[1]), r2 = f2b(v[2]), r3 = f2b(v[3]);
    out[i] = r0; out[i+1] = r1; out[i+2] = r2; out[i+3] = r3;
  }
}

__global__ __launch_bounds__(256) void k_tw(const float* __restrict__ W,
                                            u16* __restrict__ out) {
  int i = blockIdx.x * 256 + threadIdx.x;
  if (i < 16 * 1024 * 64) {
    int d = i & 63, e = (i >> 6) & 1023, h = i >> 16;
    out[(h * 64 + d) * 1024 + e] = f2b(W[i]);
  }
}

__global__ __launch_bounds__(256) void k_tsq(const float* __restrict__ W,
                                             u16* __restrict__ out) {
  int i = blockIdx.x * 256 + threadIdx.x;
  if (i < 1024 * 1024) {
    int n = i & 1023, kk = i >> 10;
    out[n * 1024 + kk] = f2b(W[i]);
  }
}

// ---------------- bf16 MFMA GEMM ----------------
template <int MODE>
__global__ __launch_bounds__(256) void gemm_bf16(
    const u16* __restrict__ A, const u16* __restrict__ Bt,
    void* __restrict__ outp, const float* __restrict__ bias, float ascale) {
  __shared__ u16 lA[64 * 32];
  __shared__ u16 lB[64 * 32];
  const int K = 1024;
  int tid = threadIdx.x, w = tid >> 6, lane = tid & 63;
  int lr = lane & 15, lg = lane >> 4;
  int m0 = blockIdx.y * 64, n0 = blockIdx.x * 64;
  f32x4 acc[4] = {};

  const u16* ga = A + (size_t)(m0 + (tid >> 2)) * K + (tid & 3) * 8;
  const u16* gb = Bt + (size_t)(n0 + (tid >> 2)) * K + (tid & 3) * 8;
  char* lA_base = (char*)lA + w * 1024;
  char* lB_base = (char*)lB + w * 1024;

  for (int kt = 0; kt < K; kt += 32) {
    __syncthreads();
    GLOAD16(ga + kt, lA_base);
    GLOAD16(gb + kt, lB_base);
    __syncthreads();
    short8 a = *(const short8*)&lA[(w * 16 + lr) * 32 + lg * 8];
#pragma unroll
    for (int j = 0; j < 4; ++j) {
      short8 b = *(const short8*)&lB[(j * 16 + lr) * 32 + lg * 8];
      acc[j] = mfma16(a, b, acc[j]);
    }
  }

  int mbase = m0 + w * 16 + lg * 4;
#pragma unroll
  for (int j = 0; j < 4; ++j) {
    int n = n0 + j * 16 + lr;
#pragma unroll
    for (int jj = 0; jj < 4; ++jj) {
      int m = mbase + jj;
      float v = acc[j][jj];
      if (MODE == 0) {
        int b = m >> 11, t = m & 2047, h = n >> 6, d = n & 63;
        ((u16*)outp)[(((size_t)(b * 16 + h)) * TT + t) * 64 + d] = f2b(v * ascale);
      } else if (MODE == 1) {
        int b = m >> 11, t = m & 2047, h = n >> 6, d = n & 63;
        ((u16*)outp)[(((size_t)(b * 16 + h)) * 64 + d) * TT + t] = f2b(v);
      } else {
        ((float*)outp)[(size_t)m * 1024 + n] = v + bias[n];
      }
    }
  }
}

// ---------------- fused scores + exact top-k + softmax + PV ----------------
// 512 threads (8 waves), 16 q-rows/block. u16 linear keys; radix 4+6+6;
// pass-1 histogram fused into QK with contention-free [bin][lr][lg] layout;
// refine passes scan a register-held row copy; two rows interleaved per wave.
__global__ __launch_bounds__(512, 4) void k_attn(
    const u16* __restrict__ qb, const u16* __restrict__ kb,
    const u16* __restrict__ vtb, u16* __restrict__ aob) {
  __shared__ u16 sc[ROWS * SCS];   // 65792 B: keys, then p (bf16)
  __shared__ u32 aux[2176];        // 8704 B: hist1[16][16][4] + hist2[16][64],
                                   // reused as f32 po[2][16][68] for PV
  __shared__ u32 rowmaxk[ROWS];
  __shared__ float rs[ROWS];
  // total LDS = 74624 B -> 2 blocks/CU

  u32* hist1 = aux;          // [bin 16][lr 16][lg 4]
  u32* hist2 = aux + 1024;   // [w 8][rr 2][bin 64]

  int tid = threadIdx.x, w = tid >> 6, lane = tid & 63;
  int lr = lane & 15, lg = lane >> 4;
  int t0 = blockIdx.x * ROWS;
  int bh = blockIdx.y;  // b*16 + h
  const u16* qh = qb + (size_t)bh * TT * 64;
  const u16* kh = kb + (size_t)bh * TT * 64;
  const u16* vh = vtb + (size_t)bh * 64 * TT;
  int SC = ((t0 + ROWS + 31) >> 5) << 5;  // cols rounded to PV k-step

  for (int i = tid; i < 1024; i += 512) hist1[i] = 0;
  if (tid < ROWS) rowmaxk[tid] = 0;

  // Q fragments (B operand: col=q-row=lr, k=lg*8..). q pre-scaled by 1/8.
  short8 qf0 = *(const short8*)&qh[(size_t)(t0 + lr) * 64 + lg * 8];
  short8 qf1 = *(const short8*)&qh[(size_t)(t0 + lr) * 64 + 32 + lg * 8];
  __syncthreads();

  // ---- QK^T (swapped: C[s][q]) -> u16 keys + fused 4-bit hist + row max --
  u32 kmax = 0;
  {
    int s0 = w * 16;
    short8 kf0n, kf1n;
    if (s0 < SC) {
      kf0n = *(const short8*)&kh[(size_t)(s0 + lr) * 64 + lg * 8];
      kf1n = *(const short8*)&kh[(size_t)(s0 + lr) * 64 + 32 + lg * 8];
    }
    for (; s0 < SC; s0 += 128) {
      short8 kf0 = kf0n, kf1 = kf1n;
      int sn = s0 + 128;
      if (sn < SC) {  // prefetch next tile
        kf0n = *(const short8*)&kh[(size_t)(sn + lr) * 64 + lg * 8];
        kf1n = *(const short8*)&kh[(size_t)(sn + lr) * 64 + 32 + lg * 8];
      }
      f32x4 acc = {0.f, 0.f, 0.f, 0.f};
      acc = mfma16(kf0, qf0, acc);  // A = K rows (s), B = Q rows (q cols)
      acc = mfma16(kf1, qf1, acc);
      int t = t0 + lr;        // this lane's q row
      int sbase = s0 + lg * 4;
      u32 key[4];
#pragma unroll
      for (int j = 0; j < 4; ++j) {
        float kf = fmaf(acc[j], 4096.f, 32768.f);
        kf = fminf(fmaxf(kf, 0.f), 65535.f);
        key[j] = (u32)kf;
        if (sbase + j > t) key[j] = 0;  // causal mask -> minimal key
      }
      kmax = max(kmax, max(max(key[0], key[1]), max(key[2], key[3])));
#pragma unroll
      for (int j = 0; j < 4; ++j)
        atomicAdd(&hist1[(key[j] >> 12) * 64 + lr * 4 + lg], 1u);
      *(u32x2*)&sc[lr * SCS + sbase] =
          (u32x2){key[0] | (key[1] << 16), key[2] | (key[3] << 16)};
    }
  }
  // zero-fill [SC, 2048) so register row-scans see key 0 there
  for (int r = 0; r < ROWS; ++r)
    for (int s = SC + tid * 8; s < 2048; s += 512 * 8)
      *(u32x4*)&sc[r * SCS + s] = (u32x4){0, 0, 0, 0};
  // per-row key max: lanes {lr, lr+16, lr+32, lr+48} share a row
  kmax = max(kmax, (u32)__shfl_xor((int)kmax, 16));
  kmax = max(kmax, (u32)__shfl_xor((int)kmax, 32));
  if (lane < 16) atomicMax(&rowmaxk[lane], kmax);
  __syncthreads();

  // ---- select + softmax: wave w owns rows w and w+8, interleaved ----
  {
    int row0 = w, row1 = w + 8;
    int n0 = t0 + row0 + 1, n1 = t0 + row1 + 1;
    bool sel0 = n0 > KTOP, sel1 = n1 > KTOP;  // wave-uniform

    // load both rows into registers; lane covers s = lane*8 + j*512 (+0..7)
    u32 rv0[16], rv1[16];
#pragma unroll
    for (int j = 0; j < 4; ++j) {
      u32x4 v0 = *(const u32x4*)&sc[row0 * SCS + lane * 8 + j * 512];
      u32x4 v1 = *(const u32x4*)&sc[row1 * SCS + lane * 8 + j * 512];
      rv0[j*4+0] = v0[0]; rv0[j*4+1] = v0[1]; rv0[j*4+2] = v0[2]; rv0[j*4+3] = v0[3];
      rv1[j*4+0] = v1[0]; rv1[j*4+1] = v1[1]; rv1[j*4+2] = v1[2]; rv1[j*4+3] = v1[3];
    }

    u32 keyth0 = 0, keyth1 = 0;
    int k0 = KTOP, k1 = KTOP;
    u32 pfx0 = 0, pfx1 = 0, d;
    // pass 1: merge fused histogram (bin = lane<16)
    u32 c0 = 0, c1 = 0;
    if (lane < 16) {
      u32x4 q0 = *(const u32x4*)&hist1[lane * 64 + row0 * 4];
      u32x4 q1 = *(const u32x4*)&hist1[lane * 64 + row1 * 4];
      c0 = q0[0] + q0[1] + q0[2] + q0[3];
      c1 = q1[0] + q1[1] + q1[2] + q1[3];
    }
    if (sel0) { rank64(c0, lane, k0, d); pfx0 = d; }
    if (sel1) { rank64(c1, lane, k1, d); pfx1 = d; }

    u32* h2a = &hist2[(w * 2 + 0) * 64];
    u32* h2b = &hist2[(w * 2 + 1) * 64];
    // pass 2: 6-bit (key bits 11..6), prefix = top 4 bits
    h2a[lane] = 0; h2b[lane] = 0;
    WSYNC();
#pragma unroll
    for (int i = 0; i < 16; ++i) {
      u32 p0 = rv0[i], p1 = rv1[i];
      u32 a0 = p0 & 0xFFFFu, a1 = p0 >> 16;
      u32 b0 = p1 & 0xFFFFu, b1 = p1 >> 16;
      if (sel0) {
        if ((a0 >> 12) == pfx0) atomicAdd(&h2a[(a0 >> 6) & 63u], 1u);
        if ((a1 >> 12) == pfx0) atomicAdd(&h2a[(a1 >> 6) & 63u], 1u);
      }
      if (sel1) {
        if ((b0 >> 12) == pfx1) atomicAdd(&h2b[(b0 >> 6) & 63u], 1u);
        if ((b1 >> 12) == pfx1) atomicAdd(&h2b[(b1 >> 6) & 63u], 1u);
      }
    }
    WSYNC();
    if (sel0) { rank64(h2a[lane], lane, k0, d); pfx0 = (pfx0 << 6) | d; }
    if (sel1) { rank64(h2b[lane], lane, k1, d); pfx1 = (pfx1 << 6) | d; }
    // pass 3: low 6 bits, prefix = top 10 bits
    h2a[lane] = 0; h2b[lane] = 0;
    WSYNC();
#pragma unroll
    for (int i = 0; i < 16; ++i) {
      u32 p0 = rv0[i], p1 = rv1[i];
      u32 a0 = p0 & 0xFFFFu, a1 = p0 >> 16;
      u32 b0 = p1 & 0xFFFFu, b1 = p1 >> 16;
      if (sel0) {
        if ((a0 >> 6) == pfx0) atomicAdd(&h2a[a0 & 63u], 1u);
        if ((a1 >> 6) == pfx0) atomicAdd(&h2a[a1 & 63u], 1u);
      }
      if (sel1) {
        if ((b0 >> 6) == pfx1) atomicAdd(&h2b[b0 & 63u], 1u);
        if ((b1 >> 6) == pfx1) atomicAdd(&h2b[b1 & 63u], 1u);
      }
    }
    WSYNC();
    if (sel0) { rank64(h2a[lane], lane, k0, d); keyth0 = (pfx0 << 6) | d; }
    if (sel1) { rank64(h2b[lane], lane, k1, d); keyth1 = (pfx1 << 6) | d; }

    // softmax both rows: p = exp2((key - keymax) * c2) if key >= thr
    u32 thr0 = keyth0 > 1u ? keyth0 : 1u;
    u32 thr1 = keyth1 > 1u ? keyth1 : 1u;
    u32 kmx0 = rowmaxk[row0], kmx1 = rowmaxk[row1];
    const float c2 = 1.44269504f / 4096.f;
    float sum0 = 0.f, sum1 = 0.f;
#pragma unroll
    for (int i = 0; i < 16; ++i) {
      u32 p0 = rv0[i], p1 = rv1[i];
      u32 a0 = p0 & 0xFFFFu, a1 = p0 >> 16;
      u32 b0 = p1 & 0xFFFFu, b1 = p1 >> 16;
      float pa0 = (a0 >= thr0) ? exp2f((float)(int)(a0 - kmx0) * c2) : 0.f;
      float pa1 = (a1 >= thr0) ? exp2f((float)(int)(a1 - kmx0) * c2) : 0.f;
      float pb0 = (b0 >= thr1) ? exp2f((float)(int)(b0 - kmx1) * c2) : 0.f;
      float pb1 = (b1 >= thr1) ? exp2f((float)(int)(b1 - kmx1) * c2) : 0.f;
      sum0 += pa0 + pa1;
      sum1 += pb0 + pb1;
      rv0[i] = (u32)f2b(pa0) | ((u32)f2b(pa1) << 16);
      rv1[i] = (u32)f2b(pb0) | ((u32)f2b(pb1) << 16);
    }
#pragma unroll
    for (int off = 32; off; off >>= 1) {
      sum0 += __shfl_xor(sum0, off);
      sum1 += __shfl_xor(sum1, off);
    }
    // write p (bf16) back
#pragma unroll
    for (int j = 0; j < 4; ++j) {
      *(u32x4*)&sc[row0 * SCS + lane * 8 + j * 512] =
          (u32x4){rv0[j*4+0], rv0[j*4+1], rv0[j*4+2], rv0[j*4+3]};
      *(u32x4*)&sc[row1 * SCS + lane * 8 + j * 512] =
          (u32x4){rv1[j*4+0], rv1[j*4+1], rv1[j*4+2], rv1[j*4+3]};
    }
    if (lane == 0) {
      rs[row0] = 1.f / fmaxf(sum0, 1e-30f);
      rs[row1] = 1.f / fmaxf(sum1, 1e-30f);
    }
  }
  __syncthreads();

  // ---- PV: O[t][d] = sum_s P[t][s] V[s][d]; 4 d-groups x 2 k-halves ----
  float* po = (float*)aux;  // [2][16][68] f32 partials (hists dead now)
  int d0 = (w & 3) * 16;
  int h = w >> 2;
  int tiles = SC >> 5;
  int mid = ((tiles + 1) >> 1) << 5;
  int kb0 = h ? mid : 0;
  int kb1 = h ? SC : mid;
  f32x4 o = {0.f, 0.f, 0.f, 0.f};
  {
    int kk = kb0;
    short8 bn;
    if (kk < kb1)
      bn = *(const short8*)&vh[(size_t)(d0 + lr) * TT + kk + lg * 8];
    for (; kk < kb1; kk += 32) {
      short8 b = bn;
      int kn = kk + 32;
      if (kn < kb1)  // prefetch next V fragment
        bn = *(const short8*)&vh[(size_t)(d0 + lr) * TT + kn + lg * 8];
      short8 a = *(const short8*)&sc[lr * SCS + kk + lg * 8];
      o = mfma16(a, b, o);
    }
  }
#pragma unroll
  for (int j = 0; j < 4; ++j)
    po[(h * ROWS + lg * 4 + j) * 68 + d0 + lr] = o[j];
  __syncthreads();

  if (w < 4) {
    int b_ = bh >> 4, h_ = bh & 15;
    int dd0 = w * 16;
#pragma unroll
    for (int j = 0; j < 4; ++j) {
      int row = lg * 4 + j;
      float val = (po[row * 68 + dd0 + lr] + po[(ROWS + row) * 68 + dd0 + lr]) *
                  rs[row];
      aob[((size_t)(b_ * TT + t0 + row)) * 1024 + h_ * 64 + dd0 + lr] = f2b(val);
    }
  }
}

// ---------------- launch ----------------

extern "C" void kernel_launch(void* const* d_in, const int* in_sizes, int n_in,
                              void* d_out, int out_size, void* d_ws, size_t ws_size,
                              hipStream_t stream) {
  const float* index  = (const float*)d_in[0];
  const float* memory = (const float*)d_in[1];
  const float* Wq     = (const float*)d_in[2];
  const float* Wk     = (const float*)d_in[3];
  const float* Wv     = (const float*)d_in[4];
  const float* Wp     = (const float*)d_in[5];
  const float* bp     = (const float*)d_in[6];

  char* ws = (char*)d_ws;
  const size_t MB = 1024 * 1024;
  u16* xbi = (u16*)(ws + 0);
  u16* xbm = (u16*)(ws + 8 * MB);
  u16* wqt = (u16*)(ws + 16 * MB);
  u16* wkt = (u16*)(ws + 18 * MB);
  u16* wvt = (u16*)(ws + 20 * MB);
  u16* wpt = (u16*)(ws + 22 * MB);
  u16* qb  = (u16*)(ws + 24 * MB);
  u16* kbf = (u16*)(ws + 32 * MB);
  u16* vtb = (u16*)(ws + 40 * MB);
  u16* aob = xbi;  // reuse

  k_cast<<<4096, 256, 0, stream>>>(index, xbi, 4096 * 1024);
  k_cast<<<4096, 256, 0, stream>>>(memory, xbm, 4096 * 1024);
  k_tw<<<4096, 256, 0, stream>>>(Wq, wqt);
  k_tw<<<4096, 256, 0, stream>>>(Wk, wkt);
  k_tw<<<4096, 256, 0, stream>>>(Wv, wvt);
  k_tsq<<<4096, 256, 0, stream>>>(Wp, wpt);

  dim3 g(16, 64);
  // q pre-scaled by HEAD^-0.5 = 0.125 so QK^T yields final scores
  gemm_bf16<0><<<g, 256, 0, stream>>>(xbi, wqt, (void*)qb, nullptr, 0.125f);
  gemm_bf16<0><<<g, 256, 0, stream>>>(xbm, wkt, (void*)kbf, nullptr, 1.f);
  gemm_bf16<1><<<g, 256, 0, stream>>>(xbm, wvt, (void*)vtb, nullptr, 1.f);

  k_attn<<<dim3(TT / ROWS, 32), 512, 0, stream>>>(qb, kbf, vtb, aob);

  gemm_bf16<2><<<g, 256, 0, stream>>>(aob, wpt, d_out, bp, 1.f);
}

// Round 5
// 338.829 us; speedup vs baseline: 3.1836x; 1.0554x over previous
//
#include <hip/hip_runtime.h>
#include <hip/hip_bf16.h>

// Problem constants (B=2, T=S=2048, EMBED=1024, H=16, D=64, top-k=204)
#define TT 2048
#define KTOP 204
#define ROWS 16
#define SCS 2056  // u16 stride per score row (4112 B, 16B-aligned)

typedef float f32x4 __attribute__((ext_vector_type(4)));
typedef short short8 __attribute__((ext_vector_type(8)));
typedef unsigned short u16;
typedef unsigned int u32;
typedef u32 u32x2 __attribute__((ext_vector_type(2)));
typedef u32 u32x4 __attribute__((ext_vector_type(4)));

#define NEG_INF (-__builtin_inff())

static __device__ __forceinline__ f32x4 mfma16(short8 a, short8 b, f32x4 c) {
  return __builtin_amdgcn_mfma_f32_16x16x32_bf16(a, b, c, 0, 0, 0);
}

static __device__ __forceinline__ u16 f2b(float f) {
  __hip_bfloat16 h = __float2bfloat16(f);
  return *reinterpret_cast<u16*>(&h);
}

// pack two finite non-negative floats as bf16 pair with RNE (no NaN handling)
static __device__ __forceinline__ u32 pack_bf16(float a, float b) {
  u32 ua = __float_as_uint(a), ub = __float_as_uint(b);
  ua = (ua + 0x7FFFu + ((ua >> 16) & 1u)) >> 16;
  ub = (ub + 0x7FFFu + ((ub >> 16) & 1u)) & 0xFFFF0000u;
  return ua | ub;
}

#define GLOAD16(gp, lp) __builtin_amdgcn_global_load_lds( \
    (const __attribute__((address_space(1))) void*)(gp),  \
    (__attribute__((address_space(3))) void*)(lp), 16, 0, 0)

// wave-local LDS ordering fence (per-wave private buffers only)
#define WSYNC() do { __builtin_amdgcn_wave_barrier(); \
    asm volatile("s_waitcnt lgkmcnt(0)" ::: "memory"); \
    __builtin_amdgcn_wave_barrier(); } while (0)

// 64-bin rank: cnt per lane (bin = lane). Finds the bin holding the k-th
// largest (counting from bin 63 down); k becomes the residual rank in-bin.
static __device__ __forceinline__ void rank64(u32 cnt, int lane, int& k,
                                              u32& dig) {
  int suf = (int)cnt;  // inclusive suffix sum over bins lane..63
#pragma unroll
  for (int off = 1; off < 64; off <<= 1) {
    int o = __shfl_down(suf, off);
    suf += (lane + off < 64) ? o : 0;
  }
  int above = suf - (int)cnt;  // count in bins above this lane's
  bool found = (above < k) && (above + (int)cnt >= k);  // unique lane
  unsigned long long ball = __ballot(found);
  int src = __ffsll((long long)ball) - 1;
  int nk = k - above;
  k = __shfl(nk, src);
  dig = (u32)src;
}

// ---------------- select + softmax (register-resident, bounded) ----------
// Wave w owns rows w and w+8 of the block. JMAX = ceil(SC/512); each lane
// holds slots s = lane*8 + j*512 + [0..7] for j < JMAX.
template <int JMAX>
static __device__ __forceinline__ void select_softmax(
    u16* __restrict__ sc, const u32* __restrict__ hist1,
    u32* __restrict__ hist2, const u32* __restrict__ rowmaxk,
    float* __restrict__ rs, int w, int lane, int t0) {
  const int NI = JMAX * 4;
  int row0 = w, row1 = w + 8;
  int n0 = t0 + row0 + 1, n1 = t0 + row1 + 1;
  bool sel0 = n0 > KTOP, sel1 = n1 > KTOP;  // wave-uniform

  u32 rv0[NI], rv1[NI];
#pragma unroll
  for (int j = 0; j < JMAX; ++j) {
    u32x4 v0 = *(const u32x4*)&sc[row0 * SCS + lane * 8 + j * 512];
    u32x4 v1 = *(const u32x4*)&sc[row1 * SCS + lane * 8 + j * 512];
    rv0[j*4+0] = v0[0]; rv0[j*4+1] = v0[1]; rv0[j*4+2] = v0[2]; rv0[j*4+3] = v0[3];
    rv1[j*4+0] = v1[0]; rv1[j*4+1] = v1[1]; rv1[j*4+2] = v1[2]; rv1[j*4+3] = v1[3];
  }

  u32 keyth0 = 0, keyth1 = 0;
  int k0 = KTOP, k1 = KTOP;
  u32 pfx0 = 0, pfx1 = 0, d;
  // pass 1 (4-bit): merge QK-fused histogram (bin = lane < 16)
  u32 c0 = 0, c1 = 0;
  if (lane < 16) {
    u32x4 q0 = *(const u32x4*)&hist1[lane * 64 + row0 * 4];
    u32x4 q1 = *(const u32x4*)&hist1[lane * 64 + row1 * 4];
    c0 = q0[0] + q0[1] + q0[2] + q0[3];
    c1 = q1[0] + q1[1] + q1[2] + q1[3];
  }
  if (sel0) { rank64(c0, lane, k0, d); pfx0 = d; }
  if (sel1) { rank64(c1, lane, k1, d); pfx1 = d; }

  u32* h2a = &hist2[(w * 2 + 0) * 64];
  u32* h2b = &hist2[(w * 2 + 1) * 64];
  // pass 2 (6-bit, key bits 11..6), prefix = top 4 bits
  h2a[lane] = 0; h2b[lane] = 0;
  WSYNC();
#pragma unroll
  for (int i = 0; i < NI; ++i) {
    u32 p0 = rv0[i], p1 = rv1[i];
    u32 a0 = p0 & 0xFFFFu, a1 = p0 >> 16;
    u32 b0 = p1 & 0xFFFFu, b1 = p1 >> 16;
    if (sel0) {
      if ((a0 >> 12) == pfx0) atomicAdd(&h2a[(a0 >> 6) & 63u], 1u);
      if ((a1 >> 12) == pfx0) atomicAdd(&h2a[(a1 >> 6) & 63u], 1u);
    }
    if (sel1) {
      if ((b0 >> 12) == pfx1) atomicAdd(&h2b[(b0 >> 6) & 63u], 1u);
      if ((b1 >> 12) == pfx1) atomicAdd(&h2b[(b1 >> 6) & 63u], 1u);
    }
  }
  WSYNC();
  if (sel0) { rank64(h2a[lane], lane, k0, d); pfx0 = (pfx0 << 6) | d; }
  if (sel1) { rank64(h2b[lane], lane, k1, d); pfx1 = (pfx1 << 6) | d; }
  // pass 3 (low 6 bits), prefix = top 10 bits
  h2a[lane] = 0; h2b[lane] = 0;
  WSYNC();
#pragma unroll
  for (int i = 0; i < NI; ++i) {
    u32 p0 = rv0[i], p1 = rv1[i];
    u32 a0 = p0 & 0xFFFFu, a1 = p0 >> 16;
    u32 b0 = p1 & 0xFFFFu, b1 = p1 >> 16;
    if (sel0) {
      if ((a0 >> 6) == pfx0) atomicAdd(&h2a[a0 & 63u], 1u);
      if ((a1 >> 6) == pfx0) atomicAdd(&h2a[a1 & 63u], 1u);
    }
    if (sel1) {
      if ((b0 >> 6) == pfx1) atomicAdd(&h2b[b0 & 63u], 1u);
      if ((b1 >> 6) == pfx1) atomicAdd(&h2b[b1 & 63u], 1u);
    }
  }
  WSYNC();
  if (sel0) { rank64(h2a[lane], lane, k0, d); keyth0 = (pfx0 << 6) | d; }
  if (sel1) { rank64(h2b[lane], lane, k1, d); keyth1 = (pfx1 << 6) | d; }

  // softmax: p = exp2((key - keymax) * c2) if key >= thr else 0
  u32 thr0 = keyth0 > 1u ? keyth0 : 1u;
  u32 thr1 = keyth1 > 1u ? keyth1 : 1u;
  u32 kmx0 = rowmaxk[row0], kmx1 = rowmaxk[row1];
  const float c2 = 1.44269504f / 4096.f;
  float sum0 = 0.f, sum1 = 0.f;
#pragma unroll
  for (int i = 0; i < NI; ++i) {
    u32 p0 = rv0[i], p1 = rv1[i];
    u32 a0 = p0 & 0xFFFFu, a1 = p0 >> 16;
    u32 b0 = p1 & 0xFFFFu, b1 = p1 >> 16;
    float pa0 = (a0 >= thr0) ? exp2f((float)(int)(a0 - kmx0) * c2) : 0.f;
    float pa1 = (a1 >= thr0) ? exp2f((float)(int)(a1 - kmx0) * c2) : 0.f;
    float pb0 = (b0 >= thr1) ? exp2f((float)(int)(b0 - kmx1) * c2) : 0.f;
    float pb1 = (b1 >= thr1) ? exp2f((float)(int)(b1 - kmx1) * c2) : 0.f;
    sum0 += pa0 + pa1;
    sum1 += pb0 + pb1;
    rv0[i] = pack_bf16(pa0, pa1);
    rv1[i] = pack_bf16(pb0, pb1);
  }
#pragma unroll
  for (int off = 32; off; off >>= 1) {
    sum0 += __shfl_xor(sum0, off);
    sum1 += __shfl_xor(sum1, off);
  }
#pragma unroll
  for (int j = 0; j < JMAX; ++j) {
    *(u32x4*)&sc[row0 * SCS + lane * 8 + j * 512] =
        (u32x4){rv0[j*4+0], rv0[j*4+1], rv0[j*4+2], rv0[j*4+3]};
    *(u32x4*)&sc[row1 * SCS + lane * 8 + j * 512] =
        (u32x4){rv1[j*4+0], rv1[j*4+1], rv1[j*4+2], rv1[j*4+3]};
  }
  if (lane == 0) {
    rs[row0] = 1.f / fmaxf(sum0, 1e-30f);
    rs[row1] = 1.f / fmaxf(sum1, 1e-30f);
  }
}

// ---------------- cast / transpose-cast kernels ----------------

__global__ __launch_bounds__(256) void k_cast(const float* __restrict__ in,
                                              u16* __restrict__ out, int n) {
  int i = (blockIdx.x * 256 + threadIdx.x) * 4;
  if (i < n) {
    f32x4 v = *(const f32x4*)(in + i);
    u16 r0 = f2b(v[0]), r1 = f2b(v[1]), r2 = f2b(v[2]), r3 = f2b(v[3]);
    out[i] = r0; out[i+1] = r1; out[i+2] = r2; out[i+3] = r3;
  }
}

__global__ __launch_bounds__(256) void k_tw(const float* __restrict__ W,
                                            u16* __restrict__ out) {
  int i = blockIdx.x * 256 + threadIdx.x;
  if (i < 16 * 1024 * 64) {
    int d = i & 63, e = (i >> 6) & 1023, h = i >> 16;
    out[(h * 64 + d) * 1024 + e] = f2b(W[i]);
  }
}

__global__ __launch_bounds__(256) void k_tsq(const float* __restrict__ W,
                                             u16* __restrict__ out) {
  int i = blockIdx.x * 256 + threadIdx.x;
  if (i < 1024 * 1024) {
    int n = i & 1023, kk = i >> 10;
    out[n * 1024 + kk] = f2b(W[i]);
  }
}

// ---------------- bf16 MFMA GEMM ----------------
template <int MODE>
__global__ __launch_bounds__(256) void gemm_bf16(
    const u16* __restrict__ A, const u16* __restrict__ Bt,
    void* __restrict__ outp, const float* __restrict__ bias, float ascale) {
  __shared__ u16 lA[64 * 32];
  __shared__ u16 lB[64 * 32];
  const int K = 1024;
  int tid = threadIdx.x, w = tid >> 6, lane = tid & 63;
  int lr = lane & 15, lg = lane >> 4;
  int m0 = blockIdx.y * 64, n0 = blockIdx.x * 64;
  f32x4 acc[4] = {};

  const u16* ga = A + (size_t)(m0 + (tid >> 2)) * K + (tid & 3) * 8;
  const u16* gb = Bt + (size_t)(n0 + (tid >> 2)) * K + (tid & 3) * 8;
  char* lA_base = (char*)lA + w * 1024;
  char* lB_base = (char*)lB + w * 1024;

  for (int kt = 0; kt < K; kt += 32) {
    __syncthreads();
    GLOAD16(ga + kt, lA_base);
    GLOAD16(gb + kt, lB_base);
    __syncthreads();
    short8 a = *(const short8*)&lA[(w * 16 + lr) * 32 + lg * 8];
#pragma unroll
    for (int j = 0; j < 4; ++j) {
      short8 b = *(const short8*)&lB[(j * 16 + lr) * 32 + lg * 8];
      acc[j] = mfma16(a, b, acc[j]);
    }
  }

  int mbase = m0 + w * 16 + lg * 4;
#pragma unroll
  for (int j = 0; j < 4; ++j) {
    int n = n0 + j * 16 + lr;
#pragma unroll
    for (int jj = 0; jj < 4; ++jj) {
      int m = mbase + jj;
      float v = acc[j][jj];
      if (MODE == 0) {
        int b = m >> 11, t = m & 2047, h = n >> 6, d = n & 63;
        ((u16*)outp)[(((size_t)(b * 16 + h)) * TT + t) * 64 + d] = f2b(v * ascale);
      } else if (MODE == 1) {
        int b = m >> 11, t = m & 2047, h = n >> 6, d = n & 63;
        ((u16*)outp)[(((size_t)(b * 16 + h)) * 64 + d) * TT + t] = f2b(v);
      } else {
        ((float*)outp)[(size_t)m * 1024 + n] = v + bias[n];
      }
    }
  }
}

// ---------------- fused scores + exact top-k + softmax + PV ----------------
__global__ __launch_bounds__(512, 4) void k_attn(
    const u16* __restrict__ qb, const u16* __restrict__ kb,
    const u16* __restrict__ vtb, u16* __restrict__ aob) {
  __shared__ u16 sc[ROWS * SCS];   // 65792 B: keys, then p (bf16)
  __shared__ u32 aux[2176];        // 8704 B: hist1[16][16][4] + hist2[16][64],
                                   // reused as f32 po[2][16][68] for PV
  __shared__ u32 rowmaxk[ROWS];
  __shared__ float rs[ROWS];
  // total LDS = 74752 B -> 2 blocks/CU

  u32* hist1 = aux;          // [bin 16][lr 16][lg 4]
  u32* hist2 = aux + 1024;   // [w 8][rr 2][bin 64]

  int tid = threadIdx.x, w = tid >> 6, lane = tid & 63;
  int lr = lane & 15, lg = lane >> 4;
  int t0 = blockIdx.x * ROWS;
  int bh = blockIdx.y;  // b*16 + h
  const u16* qh = qb + (size_t)bh * TT * 64;
  const u16* kh = kb + (size_t)bh * TT * 64;
  const u16* vh = vtb + (size_t)bh * 64 * TT;
  int SC = ((t0 + ROWS + 31) >> 5) << 5;  // cols rounded to PV k-step
  int jmax = (SC + 511) >> 9;             // 512-slot chunks per row (1..4)

  for (int i = tid; i < 1024; i += 512) hist1[i] = 0;
  if (tid < ROWS) rowmaxk[tid] = 0;

  // Q fragments (B operand: col=q-row=lr, k=lg*8..). q pre-scaled by 1/8.
  short8 qf0 = *(const short8*)&qh[(size_t)(t0 + lr) * 64 + lg * 8];
  short8 qf1 = *(const short8*)&qh[(size_t)(t0 + lr) * 64 + 32 + lg * 8];
  __syncthreads();

  // ---- QK^T (swapped: C[s][q]) -> u16 keys + fused 4-bit hist + row max --
  // Per iteration this wave covers s in [s0, s0+16): causal-mask cases are
  // wave-uniform (all rows t >= t0).
  u32 kmax = 0;
  for (int s0 = w * 16; s0 < SC; s0 += 128) {
    int sbase = s0 + lg * 4;
    if (s0 > t0 + 15) {  // fully above diagonal: all masked, keys 0
      *(u32x2*)&sc[lr * SCS + sbase] = (u32x2){0u, 0u};
      continue;
    }
    short8 kf0 = *(const short8*)&kh[(size_t)(s0 + lr) * 64 + lg * 8];
    short8 kf1 = *(const short8*)&kh[(size_t)(s0 + lr) * 64 + 32 + lg * 8];
    f32x4 acc = {0.f, 0.f, 0.f, 0.f};
    acc = mfma16(kf0, qf0, acc);  // A = K rows (s), B = Q rows (q cols)
    acc = mfma16(kf1, qf1, acc);
    u32 key[4];
    if (s0 + 15 <= t0) {  // fully below diagonal: no masking needed
#pragma unroll
      for (int j = 0; j < 4; ++j) {
        float kf = fmaf(acc[j], 4096.f, 32768.f);
        key[j] = (u32)fminf(fmaxf(kf, 0.f), 65535.f);
      }
    } else {              // diagonal tile: per-element mask
      int t = t0 + lr;
#pragma unroll
      for (int j = 0; j < 4; ++j) {
        float kf = fmaf(acc[j], 4096.f, 32768.f);
        key[j] = (u32)fminf(fmaxf(kf, 0.f), 65535.f);
        if (sbase + j > t) key[j] = 0;
      }
    }
    kmax = max(kmax, max(max(key[0], key[1]), max(key[2], key[3])));
#pragma unroll
    for (int j = 0; j < 4; ++j)
      atomicAdd(&hist1[(key[j] >> 12) * 64 + lr * 4 + lg], 1u);
    *(u32x2*)&sc[lr * SCS + sbase] =
        (u32x2){key[0] | (key[1] << 16), key[2] | (key[3] << 16)};
  }
  // zero-fill [SC, jmax*512) so register row-scans see key 0 there
  {
    int fillEnd = jmax << 9;
    for (int r = 0; r < ROWS; ++r)
      for (int s = SC + tid * 8; s < fillEnd; s += 512 * 8)
        *(u32x4*)&sc[r * SCS + s] = (u32x4){0, 0, 0, 0};
  }
  // per-row key max: lanes {lr, lr+16, lr+32, lr+48} share a row
  kmax = max(kmax, (u32)__shfl_xor((int)kmax, 16));
  kmax = max(kmax, (u32)__shfl_xor((int)kmax, 32));
  if (lane < 16) atomicMax(&rowmaxk[lane], kmax);
  __syncthreads();

  // ---- select + softmax, trip counts bound by jmax (block-uniform) ----
  switch (jmax) {
    case 1: select_softmax<1>(sc, hist1, hist2, rowmaxk, rs, w, lane, t0); break;
    case 2: select_softmax<2>(sc, hist1, hist2, rowmaxk, rs, w, lane, t0); break;
    case 3: select_softmax<3>(sc, hist1, hist2, rowmaxk, rs, w, lane, t0); break;
    default: select_softmax<4>(sc, hist1, hist2, rowmaxk, rs, w, lane, t0); break;
  }
  __syncthreads();

  // ---- PV: O[t][d] = sum_s P[t][s] V[s][d]; 4 d-groups x 2 k-halves ----
  float* po = (float*)aux;  // [2][16][68] f32 partials (hists dead now)
  int d0 = (w & 3) * 16;
  int h = w >> 2;
  int tiles = SC >> 5;
  int mid = ((tiles + 1) >> 1) << 5;
  int kb0 = h ? mid : 0;
  int kb1 = h ? SC : mid;
  f32x4 o = {0.f, 0.f, 0.f, 0.f};
  {
    int kk = kb0;
    short8 bn;
    if (kk < kb1)
      bn = *(const short8*)&vh[(size_t)(d0 + lr) * TT + kk + lg * 8];
    for (; kk < kb1; kk += 32) {
      short8 b = bn;
      int kn = kk + 32;
      if (kn < kb1)  // prefetch next V fragment
        bn = *(const short8*)&vh[(size_t)(d0 + lr) * TT + kn + lg * 8];
      short8 a = *(const short8*)&sc[lr * SCS + kk + lg * 8];
      o = mfma16(a, b, o);
    }
  }
#pragma unroll
  for (int j = 0; j < 4; ++j)
    po[(h * ROWS + lg * 4 + j) * 68 + d0 + lr] = o[j];
  __syncthreads();

  if (w < 4) {
    int b_ = bh >> 4, h_ = bh & 15;
    int dd0 = w * 16;
#pragma unroll
    for (int j = 0; j < 4; ++j) {
      int row = lg * 4 + j;
      float val = (po[row * 68 + dd0 + lr] + po[(ROWS + row) * 68 + dd0 + lr]) *
                  rs[row];
      aob[((size_t)(b_ * TT + t0 + row)) * 1024 + h_ * 64 + dd0 + lr] = f2b(val);
    }
  }
}

// ---------------- launch ----------------

extern "C" void kernel_launch(void* const* d_in, const int* in_sizes, int n_in,
                              void* d_out, int out_size, void* d_ws, size_t ws_size,
                              hipStream_t stream) {
  const float* index  = (const float*)d_in[0];
  const float* memory = (const float*)d_in[1];
  const float* Wq     = (const float*)d_in[2];
  const float* Wk     = (const float*)d_in[3];
  const float* Wv     = (const float*)d_in[4];
  const float* Wp     = (const float*)d_in[5];
  const float* bp     = (const float*)d_in[6];

  char* ws = (char*)d_ws;
  const size_t MB = 1024 * 1024;
  u16* xbi = (u16*)(ws + 0);
  u16* xbm = (u16*)(ws + 8 * MB);
  u16* wqt = (u16*)(ws + 16 * MB);
  u16* wkt = (u16*)(ws + 18 * MB);
  u16* wvt = (u16*)(ws + 20 * MB);
  u16* wpt = (u16*)(ws + 22 * MB);
  u16* qb  = (u16*)(ws + 24 * MB);
  u16* kbf = (u16*)(ws + 32 * MB);
  u16* vtb = (u16*)(ws + 40 * MB);
  u16* aob = xbi;  // reuse

  k_cast<<<4096, 256, 0, stream>>>(index, xbi, 4096 * 1024);
  k_cast<<<4096, 256, 0, stream>>>(memory, xbm, 4096 * 1024);
  k_tw<<<4096, 256, 0, stream>>>(Wq, wqt);
  k_tw<<<4096, 256, 0, stream>>>(Wk, wkt);
  k_tw<<<4096, 256, 0, stream>>>(Wv, wvt);
  k_tsq<<<4096, 256, 0, stream>>>(Wp, wpt);

  dim3 g(16, 64);
  // q pre-scaled by HEAD^-0.5 = 0.125 so QK^T yields final scores
  gemm_bf16<0><<<g, 256, 0, stream>>>(xbi, wqt, (void*)qb, nullptr, 0.125f);
  gemm_bf16<0><<<g, 256, 0, stream>>>(xbm, wkt, (void*)kbf, nullptr, 1.f);
  gemm_bf16<1><<<g, 256, 0, stream>>>(xbm, wvt, (void*)vtb, nullptr, 1.f);

  k_attn<<<dim3(TT / ROWS, 32), 512, 0, stream>>>(qb, kbf, vtb, aob);

  gemm_bf16<2><<<g, 256, 0, stream>>>(aob, wpt, d_out, bp, 1.f);
}